// Round 2
// 187.916 us; speedup vs baseline: 1.3713x; 1.3713x over previous
//
#include <hip/hip_runtime.h>
#include <hip/hip_bf16.h>
#include <stdint.h>
#include <stddef.h>

typedef __attribute__((ext_vector_type(4))) float f32x4;
typedef _Float16 f16x8 __attribute__((ext_vector_type(8)));
typedef _Float16 f16x4 __attribute__((ext_vector_type(4)));

#define BN 128
// coarse scores are in 2^20-scaled units: sc = 2^20*(||e||^2 - 2 z.e) + eps.
// margin = (np grid ~6e-5 + >>8 sigma of fp16 coarse error ~6.4e-6) * 2^20
#define MARGIN 230.0f

// norm table lives in module-static device memory (NOT workspace: ws_size may
// be exactly the 512 KB embf needs; overrunning it can corrupt the heap).
__device__ float g_embn[1024];

// prep: embf = fp16(e*1024) [1024][256]; g_embn = 2^20*||e'||^2 f32[1024]
// (norm computed from the fp16-rounded values -> consistent with MFMA scores;
//  summation-order eps ~1e-3 << MARGIN slack)
__global__ __launch_bounds__(256) void emb_prep_kernel(const float* __restrict__ emb,
                                                       _Float16* __restrict__ embf) {
    int row = blockIdx.x * 4 + (threadIdx.x >> 6);   // 256 blocks x 4 rows
    int l   = threadIdx.x & 63;
    f32x4 v = *(const f32x4*)&emb[(size_t)row * 256 + l * 4];
    f16x4 h;
    float s = 0.f;
#pragma unroll
    for (int j = 0; j < 4; ++j) {
        h[j] = (_Float16)(v[j] * 1024.0f);   // *2^10 exact, then RNE cvt
        float f = (float)h[j];
        s = fmaf(f, f, s);
    }
    *(f16x4*)&embf[(size_t)row * 256 + l * 4] = h;
#pragma unroll
    for (int off = 1; off < 64; off <<= 1) s += __shfl_xor(s, off, 64);
    if (l == 0) g_embn[row] = s;
}

// ---------------------------------------------------------------------------
// B-chunk DMA: emb'[kt*128..+128][ds*32..+32] -> LDS [128 codes][4 slots][8]
// slot s of code k holds global grp g = (s ^ k ^ (k>>2)) & 3  (swizzled).
// global_load_lds width=16, wave-uniform base + lane*16. 512 threads = 1 ld ea.
// ---------------------------------------------------------------------------
__device__ __forceinline__ void prefetch_B(const _Float16* __restrict__ embf,
                                           _Float16* bbuf, int s, int t) {
    int kt = s >> 3, ds = s & 7;
    int code = t >> 2;
    int slot = t & 3;
    int g    = (slot ^ code ^ (code >> 2)) & 3;
    const _Float16* src = embf + (((size_t)(kt * 128 + code)) << 8) + ds * 32 + g * 8;
    void* dst = (void*)(bbuf + (size_t)t * 8);
    __builtin_amdgcn_global_load_lds((const __attribute__((address_space(1))) void*)src,
                                     (__attribute__((address_space(3))) void*)dst,
                                     16, 0, 0);
}

// ---------------------------------------------------------------------------
// Fused VQ: fp16 MFMA coarse pass (scaled score = e'norm - 2048*dot, best-2) +
// wave-cooperative bit-exact numpy-f32 rescore of near-tie rows via worklist.
// 512 threads / 8 waves: wr = w>>1 (32-row quarter), wc = w&1 (64-code half).
// ---------------------------------------------------------------------------
__global__ __launch_bounds__(512, 4) void vq_kernel(
        const float* __restrict__ z,
        const float* __restrict__ emb,
        const _Float16* __restrict__ embf,
        float* __restrict__ out) {

    __shared__ _Float16 A_sh[BN * 256];        // 64 KB fp16 z tile
    __shared__ _Float16 B_sh[2][BN * 32];      // 16 KB dbuf emb chunks

    const int t  = threadIdx.x;
    const int w  = t >> 6;   // 0..7
    const int l  = t & 63;
    const int c  = l & 15;   // MFMA N-lane
    const int q  = l >> 4;   // MFMA quad
    const int wr = w >> 1;   // row quarter (32 rows)
    const int wc = w & 1;    // code half  (64 codes)

    const int n0    = blockIdx.x * BN;
    const int b_img = n0 >> 12;
    const int hw0   = n0 & 4095;
    const float* zb = z + (size_t)b_img * (256 * 4096) + hw0;

    // ---- Stage A: z NCHW f32 -> fp16 [n][d], transposed, swizzled ----
#pragma unroll
    for (int it = 0; it < 2; ++it) {
        int task = it * 512 + t;      // 32 nquad x 32 dgroups
        int nq = task & 31;           // lane-contiguous -> 512B coalesced
        int dg = task >> 5;
        const float* g = zb + (size_t)(dg * 8) * 4096 + nq * 4;
        f32x4 col[8];
#pragma unroll
        for (int j = 0; j < 8; ++j) col[j] = *(const f32x4*)(g + (size_t)j * 4096);
#pragma unroll
        for (int u = 0; u < 4; ++u) {
            int n = nq * 4 + u;
            f16x8 v;
#pragma unroll
            for (int j = 0; j < 8; ++j) v[j] = (_Float16)col[j][u];
            *(f16x8*)&A_sh[n * 256 + ((dg ^ (n & 7)) * 8)] = v;
        }
    }
    __syncthreads();

    prefetch_B(embf, &B_sh[0][0], 0, t);

    f32x4 acc[2][4];
    float v1[8], v2[8];
    int   i1[8], i2[8];
#pragma unroll
    for (int i = 0; i < 2; ++i)
#pragma unroll
        for (int j = 0; j < 4; ++j) acc[i][j] = (f32x4){0.f, 0.f, 0.f, 0.f};
#pragma unroll
    for (int p = 0; p < 8; ++p) { v1[p] = 3.4e38f; v2[p] = 3.4e38f; i1[p] = 0x7fffffff; i2[p] = 0x7fffffff; }

    for (int kt = 0; kt < 8; ++kt) {
        // issue the 4 norm loads early; consumed in the kt epilogue (L1-hot 4KB)
        float en4[4];
#pragma unroll
        for (int j = 0; j < 4; ++j) en4[j] = g_embn[kt * 128 + wc * 64 + j * 16 + c];

#pragma unroll
        for (int ds = 0; ds < 8; ++ds) {
            int s = kt * 8 + ds;
            __syncthreads();                                   // drains prefetch(s)
            if (s + 1 < 64) prefetch_B(embf, &B_sh[(s + 1) & 1][0], s + 1, t);

            const _Float16* Bb = &B_sh[s & 1][0];

            f16x8 af[2], bfr[4];
#pragma unroll
            for (int i = 0; i < 2; ++i) {
                int n  = wr * 32 + i * 16 + c;
                int pg = ((ds << 2) + q) ^ (n & 7);
                af[i] = *(const f16x8*)&A_sh[n * 256 + pg * 8];
            }
#pragma unroll
            for (int j = 0; j < 4; ++j) {
                int k = wc * 64 + j * 16 + c;
                bfr[j] = *(const f16x8*)&Bb[k * 32 + (((q ^ k ^ (k >> 2)) & 3) * 8)];
            }
#pragma unroll
            for (int i = 0; i < 2; ++i)
#pragma unroll
                for (int j = 0; j < 4; ++j)
                    acc[i][j] = __builtin_amdgcn_mfma_f32_16x16x32_f16(af[i], bfr[j], acc[i][j], 0, 0, 0);
        }

        // ---- kt epilogue: scale-consistent score, best-2 ----
        // en = 2^20*||e||^2 (precomputed) ; acc = 2^10*(z.e)
        // sc = en - 2048*acc = 2^20*(||e||^2 - 2 z.e)  (argmin-equivalent)
#pragma unroll
        for (int j = 0; j < 4; ++j) {
            float en = en4[j];
            int code = kt * 128 + wc * 64 + j * 16 + c;
#pragma unroll
            for (int i = 0; i < 2; ++i) {
#pragma unroll
                for (int r = 0; r < 4; ++r) {
                    int p = i * 4 + r;
                    float sc = fmaf(-2048.0f, acc[i][j][r], en);
                    if (sc < v1[p]) {
                        v2[p] = v1[p]; i2[p] = i1[p];
                        v1[p] = sc;    i1[p] = code;
                    } else if (sc < v2[p]) {
                        v2[p] = sc;    i2[p] = code;
                    }
                }
            }
        }
#pragma unroll
        for (int i = 0; i < 2; ++i)
#pragma unroll
            for (int j = 0; j < 4; ++j) acc[i][j] = (f32x4){0.f, 0.f, 0.f, 0.f};
    }

    __syncthreads();   // A_sh/B_sh dead -> reuse as scratch

    // ---- dump best-2 per (lane,row), diagonal-swizzled: entry(slot,row) at
    //      [slot*128 + ((row+slot)&127)] -> scan reads stride-1, writes <=2-way
    float* cv = (float*)A_sh;              // 64 slots x 128 rows (32 KB)
    int*   ci = ((int*)A_sh) + 8192;       // 32 KB
    // worklist carved from B_sh (cap 128 = every row; no silent drop)
    int* idx_fin = (int*)&B_sh[0][0];      // 128
    int* wl_n    = idx_fin + 128;          // 1
    int* wl_row  = idx_fin + 129;          // 128
    int* wl_nc   = idx_fin + 257;          // 128
    int* wl_cand = idx_fin + 385;          // 128*8  (total 5636 B <= 16 KB)

    if (t == 0) wl_n[0] = 0;
#pragma unroll
    for (int p = 0; p < 8; ++p) {
        int row = wr * 32 + (p >> 2) * 16 + q * 4 + (p & 3);
        int s0  = (wc * 16 + c) * 2;
        cv[s0 * 128       + ((row + s0)     & 127)] = v1[p];
        ci[s0 * 128       + ((row + s0)     & 127)] = i1[p];
        cv[(s0 + 1) * 128 + ((row + s0 + 1) & 127)] = v2[p];
        ci[(s0 + 1) * 128 + ((row + s0 + 1) & 127)] = i2[p];
    }
    __syncthreads();

    if (t < BN) {
        float mv = 3.4e38f; int mi = 0x7fffffff;
#pragma unroll 8
        for (int s = 0; s < 64; ++s) {
            float v = cv[s * 128 + ((t + s) & 127)];
            int  id = ci[s * 128 + ((t + s) & 127)];
            if (v < mv || (v == mv && id < mi)) { mv = v; mi = id; }
        }
        int   cand[8]; int nc = 0;
        float thr = mv + MARGIN;
        for (int s = 0; s < 64; ++s) {
            float v = cv[s * 128 + ((t + s) & 127)];
            int  id = ci[s * 128 + ((t + s) & 127)];
            if (v <= thr && id < 1024 && nc < 8) cand[nc++] = id;
        }
        idx_fin[t] = mi;
        if (nc > 1) {
            int slot = atomicAdd(wl_n, 1);
            wl_row[slot] = t;
            wl_nc[slot]  = nc;
            for (int i = 0; i < nc; ++i) wl_cand[slot * 8 + i] = cand[i];
        }
    }
    __syncthreads();

    // ---- wave-cooperative bit-exact numpy-f32 rescore ----
    int nwl = wl_n[0];
    for (int e = w; e < nwl; e += 8) {
        int row = wl_row[e];
        int nc  = wl_nc[e];
        const float* zrow = zb + row;      // element d at zrow[d*4096]

        // a_n: np pairwise sum of z^2, 16 parallel chains (np 8-acc x 2 halves)
        int j  = l & 15, h = j >> 3, jj = j & 7;
        float x0 = zrow[(size_t)(h * 128 + jj) * 4096];
        float r  = __fmul_rn(x0, x0);
        for (int m = 1; m < 16; ++m) {
            float x = zrow[(size_t)(h * 128 + jj + 8 * m) * 4096];
            r = __fadd_rn(r, __fmul_rn(x, x));
        }
        float s1 = __fadd_rn(r,  __shfl_xor(r,  1, 64));
        float s2 = __fadd_rn(s1, __shfl_xor(s1, 2, 64));
        float s4 = __fadd_rn(s2, __shfl_xor(s2, 4, 64));
        float a_n = __fadd_rn(s4, __shfl_xor(s4, 8, 64));
        a_n = __shfl(a_n, 0, 64);

        float best = 3.4e38f; int bid = 0x7fffffff;
        for (int cx = 0; cx < nc; ++cx) {
            int id = wl_cand[e * 8 + cx];
            const float* er = emb + (size_t)id * 256;
            // b_k: same bit-exact np tree, contiguous reads
            float y0 = er[h * 128 + jj];
            float rb = __fmul_rn(y0, y0);
            for (int m = 1; m < 16; ++m) {
                float y = er[h * 128 + jj + 8 * m];
                rb = __fadd_rn(rb, __fmul_rn(y, y));
            }
            float b1 = __fadd_rn(rb, __shfl_xor(rb, 1, 64));
            float b2 = __fadd_rn(b1, __shfl_xor(b1, 2, 64));
            float b4 = __fadd_rn(b2, __shfl_xor(b2, 4, 64));
            float b_k = __fadd_rn(b4, __shfl_xor(b4, 8, 64));
            b_k = __shfl(b_k, 0, 64);
            // c: f64 dot, 64-lane butterfly (order-free, ~exact)
            double cd = 0.0;
#pragma unroll
            for (int u = 0; u < 4; ++u) {
                int d = l + u * 64;
                cd = fma((double)zrow[(size_t)d * 4096], (double)er[d], cd);
            }
#pragma unroll
            for (int off = 1; off < 64; off <<= 1) cd += __shfl_xor(cd, off, 64);
            float c32 = (float)cd;
            float sc  = __fsub_rn(__fadd_rn(a_n, b_k), __fmul_rn(2.0f, c32));
            if (sc < best || (sc == best && id < bid)) { best = sc; bid = id; }
        }
        if (l == 0) idx_fin[row] = bid;
    }
    __syncthreads();

    // ---- final index write + z_q gather ----
    if (t < BN) out[n0 + t] = (float)idx_fin[t];

    // each thread owns one spatial position m (id loaded once) and 16 d4-quads:
    // f32x4 row reads (16B/lane from L2-hot emb) + 4B/lane coalesced stores
    // (256B contiguous segments per wave-instr).
    float* zq = out + 65536 + (size_t)b_img * (256 * 4096) + hw0;
    {
        int m   = t & 127;
        int sub = t >> 7;                 // 0..3
        int id  = idx_fin[m];
        const float* er = emb + (size_t)id * 256;
#pragma unroll 4
        for (int it = 0; it < 16; ++it) {
            int d4 = it * 4 + sub;        // 0..63
            f32x4 v = *(const f32x4*)&er[d4 * 4];
#pragma unroll
            for (int jj2 = 0; jj2 < 4; ++jj2)
                zq[(size_t)(d4 * 4 + jj2) * 4096 + m] = v[jj2];
        }
    }
}

// ---------------------------------------------------------------------------
extern "C" void kernel_launch(void* const* d_in, const int* in_sizes, int n_in,
                              void* d_out, int out_size, void* d_ws, size_t ws_size,
                              hipStream_t stream) {
    const float* z   = (const float*)d_in[0];   // f32 [16,256,64,64]
    const float* emb = (const float*)d_in[1];   // f32 [1024,256]
    _Float16* embf = (_Float16*)d_ws;            // 512 KB fp16 copy (e*1024)
    float* out = (float*)d_out;

    emb_prep_kernel<<<256, 256, 0, stream>>>(emb, embf);
    vq_kernel<<<65536 / BN, 512, 0, stream>>>(z, emb, embf, out);
}